// Round 1
// baseline (67.897 us; speedup 1.0000x reference)
//
#include <hip/hip_runtime.h>

// Resample 48k -> 10k: up=5, down=24, 481-tap FIR (sum-normalized, scaled by up).
// y[n] = sum_j h5[5j+r] * x[floor(24n/5)+48-j],  r=(4n)%5
// Per thread: k fixed, outputs n=5k+d (d=0..4). Window w in [0,120):
//   g = 24k-48+w,  tap index m = 24d+480-5w  (k-independent -> wave-uniform -> SGPR)

#define NIN   1440000
#define NOUTR 300000
#define NROWS 32
#define KTOT  60000          // outputs per row / 5
#define BK    256            // k per block
#define TILE  6240           // 24*255 + 120
#define LDSN  (TILE + TILE/8)  // pad-8 swizzle

// T[wg*40 + d*8 + u] = 5 * h[24d + 480 - 5*(wg*8+u)]  (0 outside [0,480])
__global__ void prep_taps_kernel(const float* __restrict__ h, float* __restrict__ T) {
    int i = blockIdx.x * blockDim.x + threadIdx.x;
    if (i < 600) {
        int u  = i & 7;
        int d  = (i >> 3) % 5;
        int wg = i / 40;
        int w  = wg * 8 + u;
        int t  = 24 * d + 480 - 5 * w;
        T[i] = (t >= 0 && t <= 480) ? h[t] * 5.0f : 0.0f;
    }
}

__global__ __launch_bounds__(256) void resample_kernel(
    const float* __restrict__ x, const float* __restrict__ T, float* __restrict__ y)
{
    __shared__ float lds[LDSN];
    const int tid = threadIdx.x;
    const int k0  = blockIdx.x * BK;
    const int row = blockIdx.y;
    const float* __restrict__ xr = x + (size_t)row * NIN;
    const int g0 = 24 * k0 - 48;

    // Stage tile: float4 global loads, pad-8 swizzled LDS store (m = e + e/8).
    for (int i4 = tid; i4 < TILE / 4; i4 += 256) {
        const int e = i4 * 4;
        const int g = g0 + e;
        float4 v;
        if (g >= 0 && g + 3 < NIN) {
            v = *reinterpret_cast<const float4*>(xr + g);
        } else {
            v.x = (g + 0 >= 0 && g + 0 < NIN) ? xr[g + 0] : 0.0f;
            v.y = (g + 1 >= 0 && g + 1 < NIN) ? xr[g + 1] : 0.0f;
            v.z = (g + 2 >= 0 && g + 2 < NIN) ? xr[g + 2] : 0.0f;
            v.w = (g + 3 >= 0 && g + 3 < NIN) ? xr[g + 3] : 0.0f;
        }
        const int m = e + (e >> 3);   // e%4==0 -> m..m+3 contiguous within 8-group
        lds[m + 0] = v.x; lds[m + 1] = v.y; lds[m + 2] = v.z; lds[m + 3] = v.w;
    }
    __syncthreads();

    float acc0 = 0.f, acc1 = 0.f, acc2 = 0.f, acc3 = 0.f, acc4 = 0.f;
    const int base = 24 * tid;       // window start e for w=0 (multiple of 8)
    for (int wg = 0; wg < 15; ++wg) {
        const int e0 = base + wg * 8;            // aligned to 8
        const int m0 = e0 + (e0 >> 3);           // swizzled; 8 consecutive valid
        float xv[8];
        #pragma unroll
        for (int u = 0; u < 8; ++u) xv[u] = lds[m0 + u];
        const float* __restrict__ tp = T + wg * 40;   // uniform -> s_load
        #pragma unroll
        for (int u = 0; u < 8; ++u) {
            acc0 += tp[ 0 + u] * xv[u];
            acc1 += tp[ 8 + u] * xv[u];
            acc2 += tp[16 + u] * xv[u];
            acc3 += tp[24 + u] * xv[u];
            acc4 += tp[32 + u] * xv[u];
        }
    }

    const int k = k0 + tid;
    if (k < KTOT) {
        float* __restrict__ yr = y + (size_t)row * NOUTR + (size_t)5 * k;
        yr[0] = acc0; yr[1] = acc1; yr[2] = acc2; yr[3] = acc3; yr[4] = acc4;
    }
}

extern "C" void kernel_launch(void* const* d_in, const int* in_sizes, int n_in,
                              void* d_out, int out_size, void* d_ws, size_t ws_size,
                              hipStream_t stream) {
    const float* x = (const float*)d_in[0];
    const float* h = (const float*)d_in[1];   // 481 taps
    float* y = (float*)d_out;                 // 32 x 300000 f32
    float* T = (float*)d_ws;                  // 600 floats of scratch

    prep_taps_kernel<<<3, 256, 0, stream>>>(h, T);
    dim3 grid((KTOT + BK - 1) / BK, NROWS);   // 235 x 32
    resample_kernel<<<grid, 256, 0, stream>>>(x, T, y);
}